// Round 4
// baseline (16649.518 us; speedup 1.0000x reference)
//
#include <hip/hip_runtime.h>
#include <math.h>

// Problem constants
static constexpr int H  = 512;
static constexpr int B  = 32;
static constexpr int S  = 128;
static constexpr int G4 = 2048;  // 4*H

// ws layout (floats)
static constexpr size_t OFF_E   = 0;                        // E [b][t][c]; reused as D after encoder
static constexpr size_t SZ_E    = (size_t)B * S * G4;       // 8,388,608
static constexpr size_t OFF_EO  = OFF_E + SZ_E;             // enc_out [b][t][h]
static constexpr size_t SZ_EO   = (size_t)B * S * H;
static constexpr size_t OFF_PT  = OFF_EO + SZ_EO;           // P_t [b][h][s]
static constexpr size_t SZ_PT   = (size_t)B * H * S;
static constexpr size_t OFF_WET = OFF_PT + SZ_PT;           // enc WhhT [512][2048]
static constexpr size_t OFF_WDT = OFF_WET + (size_t)H * G4; // dec WhhT [512][2048]
static constexpr size_t OFF_W2T = OFF_WDT + (size_t)H * G4; // W2T [512][512]
static constexpr size_t OFF_CB  = OFF_W2T + (size_t)H * H;  // c_buf [b][h]
static constexpr size_t OFF_M1  = OFF_CB + (size_t)B * H;   // M1 [c][2]
static constexpr size_t OFF_BE  = OFF_M1 + (size_t)G4 * 2;  // bias_e [c]
static constexpr size_t OFF_DB  = OFF_BE + G4;              // dbias [c]

__device__ __forceinline__ float sigm(float x){
  float e = __expf(-x);
  return 1.0f / (1.0f + e);
}
__device__ __forceinline__ float tanh_(float x){
  float e = __expf(2.0f * x);
  return 1.0f - 2.0f / (1.0f + e);
}

// -------- prep: M1 = Wih@Wp, bias_e = Wih@bp + bih + bhh, dbias --------
__global__ __launch_bounds__(256) void prep_misc(
    const float* __restrict__ eWih, const float* __restrict__ Wp,
    const float* __restrict__ bp,  const float* __restrict__ ebih,
    const float* __restrict__ ebhh, const float* __restrict__ dbih,
    const float* __restrict__ dbhh,
    float* __restrict__ M1, float* __restrict__ bias_e, float* __restrict__ dbias)
{
  int c = blockIdx.x * 256 + threadIdx.x;   // 0..2047
  const float* wr = eWih + (size_t)c * H;
  float m0 = 0.f, m1 = 0.f, mb = 0.f;
  for (int k = 0; k < H; k += 4){
    float4 w  = *(const float4*)(wr + k);
    float4 p0 = *(const float4*)(Wp + (size_t)k * 2);
    float4 p1 = *(const float4*)(Wp + (size_t)(k + 2) * 2);
    float4 bb = *(const float4*)(bp + k);
    m0 += w.x*p0.x + w.y*p0.z + w.z*p1.x + w.w*p1.z;
    m1 += w.x*p0.y + w.y*p0.w + w.z*p1.y + w.w*p1.w;
    mb += w.x*bb.x + w.y*bb.y + w.z*bb.z + w.w*bb.w;
  }
  M1[(size_t)c*2]   = m0;
  M1[(size_t)c*2+1] = m1;
  bias_e[c] = ebih[c] + ebhh[c] + mb;
  dbias[c]  = dbih[c] + dbhh[c];
}

// -------- E fill: E[b][t][c] = M1[c]·in[b,t] + bias_e[c] --------
__global__ __launch_bounds__(256) void efill(
    const float* __restrict__ inp, const float* __restrict__ M1,
    const float* __restrict__ be, float* __restrict__ E)
{
  size_t i = (size_t)blockIdx.x * 256 + threadIdx.x;
  int c = (int)(i & 2047);
  int t = (int)((i >> 11) & 127);
  int b = (int)(i >> 18);
  float x0 = inp[((size_t)b * S + t) * 2 + 0];
  float x1 = inp[((size_t)b * S + t) * 2 + 1];
  E[i] = M1[(size_t)c*2] * x0 + M1[(size_t)c*2+1] * x1 + be[c];
}

// -------- transpose: out[K][R] = in[R][K] (R,K multiples of 32) --------
__global__ __launch_bounds__(256) void transpose_k(
    const float* __restrict__ in, float* __restrict__ out, int R, int K)
{
  __shared__ float tile[32][33];
  int r0 = blockIdx.y * 32, k0 = blockIdx.x * 32;
  int tx = threadIdx.x & 31, ty = threadIdx.x >> 5;  // ty 0..7
  #pragma unroll
  for (int j = 0; j < 4; ++j)
    tile[ty + 8*j][tx] = in[(size_t)(r0 + ty + 8*j) * K + k0 + tx];
  __syncthreads();
  #pragma unroll
  for (int j = 0; j < 4; ++j)
    out[(size_t)(k0 + ty + 8*j) * R + r0 + tx] = tile[tx][ty + 8*j];
}

// -------- generic fp32 GEMM: C = A(MxK) @ B(NxK)^T (+bias) --------
// LAYOUT 0: C[m*N+n]   LAYOUT 1: Pt[b][n][t] with m = b*128+t
template<int LAYOUT>
__global__ __launch_bounds__(256) void gemm_nt(
    const float* __restrict__ A, const float* __restrict__ Bm,
    const float* __restrict__ bias, float* __restrict__ C,
    int M, int N, int K)
{
  __shared__ float As[16][68];
  __shared__ float Bs[16][68];
  int tid = threadIdx.x;
  int bm = blockIdx.y * 64, bn = blockIdx.x * 64;
  int tm = (tid & 15) * 4, tn = (tid >> 4) * 4;
  float acc[4][4] = {};
  int r  = tid >> 2;
  int kq = (tid & 3) * 4;
  for (int k0 = 0; k0 < K; k0 += 16){
    float4 a = *(const float4*)(A  + (size_t)(bm + r) * K + k0 + kq);
    float4 b = *(const float4*)(Bm + (size_t)(bn + r) * K + k0 + kq);
    __syncthreads();
    As[kq+0][r] = a.x; As[kq+1][r] = a.y; As[kq+2][r] = a.z; As[kq+3][r] = a.w;
    Bs[kq+0][r] = b.x; Bs[kq+1][r] = b.y; Bs[kq+2][r] = b.z; Bs[kq+3][r] = b.w;
    __syncthreads();
    #pragma unroll
    for (int kk = 0; kk < 16; ++kk){
      float4 av = *(const float4*)(&As[kk][tm]);
      float4 bv = *(const float4*)(&Bs[kk][tn]);
      acc[0][0] += av.x*bv.x; acc[0][1] += av.x*bv.y; acc[0][2] += av.x*bv.z; acc[0][3] += av.x*bv.w;
      acc[1][0] += av.y*bv.x; acc[1][1] += av.y*bv.y; acc[1][2] += av.y*bv.z; acc[1][3] += av.y*bv.w;
      acc[2][0] += av.z*bv.x; acc[2][1] += av.z*bv.y; acc[2][2] += av.z*bv.z; acc[2][3] += av.z*bv.w;
      acc[3][0] += av.w*bv.x; acc[3][1] += av.w*bv.y; acc[3][2] += av.w*bv.z; acc[3][3] += av.w*bv.w;
    }
  }
  #pragma unroll
  for (int i = 0; i < 4; ++i){
    int m = bm + tm + i;
    #pragma unroll
    for (int j = 0; j < 4; ++j){
      int n = bn + tn + j;
      float vv = acc[i][j] + (bias ? bias[n] : 0.f);
      if (LAYOUT == 0) C[(size_t)m * N + n] = vv;
      else             C[((size_t)(m >> 7) * 512 + n) * 128 + (m & 127)] = vv;
    }
  }
}

// gates GEMV: acc[0..3] = rows 4*tid.., acc[4..7] = rows 1024+4*tid..
// g[row] = sum_k WT[k][row] * hsh[k]
__device__ __forceinline__ void gates_gemv(
    const float* __restrict__ WT, const float* hsh, int tid,
    float4& accA, float4& accB)
{
  accA = {0.f,0.f,0.f,0.f};
  accB = {0.f,0.f,0.f,0.f};
  #pragma unroll 2
  for (int k = 0; k < H; k += 4){
    float4 hv = *(const float4*)&hsh[k];     // uniform broadcast
    const float* wk = WT + (size_t)k * G4 + (tid << 2);
    float4 a0 = *(const float4*)(wk);
    float4 b0 = *(const float4*)(wk + 1024);
    float4 a1 = *(const float4*)(wk + G4);
    float4 b1 = *(const float4*)(wk + G4 + 1024);
    float4 a2 = *(const float4*)(wk + 2*G4);
    float4 b2 = *(const float4*)(wk + 2*G4 + 1024);
    float4 a3 = *(const float4*)(wk + 3*G4);
    float4 b3 = *(const float4*)(wk + 3*G4 + 1024);
    accA.x = fmaf(a0.x,hv.x,accA.x); accA.y = fmaf(a0.y,hv.x,accA.y);
    accA.z = fmaf(a0.z,hv.x,accA.z); accA.w = fmaf(a0.w,hv.x,accA.w);
    accB.x = fmaf(b0.x,hv.x,accB.x); accB.y = fmaf(b0.y,hv.x,accB.y);
    accB.z = fmaf(b0.z,hv.x,accB.z); accB.w = fmaf(b0.w,hv.x,accB.w);
    accA.x = fmaf(a1.x,hv.y,accA.x); accA.y = fmaf(a1.y,hv.y,accA.y);
    accA.z = fmaf(a1.z,hv.y,accA.z); accA.w = fmaf(a1.w,hv.y,accA.w);
    accB.x = fmaf(b1.x,hv.y,accB.x); accB.y = fmaf(b1.y,hv.y,accB.y);
    accB.z = fmaf(b1.z,hv.y,accB.z); accB.w = fmaf(b1.w,hv.y,accB.w);
    accA.x = fmaf(a2.x,hv.z,accA.x); accA.y = fmaf(a2.y,hv.z,accA.y);
    accA.z = fmaf(a2.z,hv.z,accA.z); accA.w = fmaf(a2.w,hv.z,accA.w);
    accB.x = fmaf(b2.x,hv.z,accB.x); accB.y = fmaf(b2.y,hv.z,accB.y);
    accB.z = fmaf(b2.z,hv.z,accB.z); accB.w = fmaf(b2.w,hv.z,accB.w);
    accA.x = fmaf(a3.x,hv.w,accA.x); accA.y = fmaf(a3.y,hv.w,accA.y);
    accA.z = fmaf(a3.z,hv.w,accA.z); accA.w = fmaf(a3.w,hv.w,accA.w);
    accB.x = fmaf(b3.x,hv.w,accB.x); accB.y = fmaf(b3.y,hv.w,accB.y);
    accB.z = fmaf(b3.z,hv.w,accB.z); accB.w = fmaf(b3.w,hv.w,accB.w);
  }
}

// -------- per-batch encoder: grid=32 blocks, 1 block per batch, no grid sync --------
__global__ __launch_bounds__(256) void encoder_kernel(
    const float* __restrict__ WT,     // enc WhhT [512][2048]
    const float* __restrict__ E,      // [b][t][c]
    float* __restrict__ enc_out,      // [b][t][h]
    float* __restrict__ c_buf)        // [b][h]
{
  __shared__ float hsh[H];
  __shared__ float gsh[G4];
  const int tid = threadIdx.x, b = blockIdx.x;
  hsh[tid] = 0.f; hsh[tid + 256] = 0.f;
  float c0 = 0.f, c1 = 0.f;           // cell state for units tid, tid+256
  const float* Eb = E + (size_t)b * S * G4;
  __syncthreads();
  for (int t = 0; t < S; ++t){
    float4 accA, accB;
    gates_gemv(WT, hsh, tid, accA, accB);
    const float* Et = Eb + (size_t)t * G4 + (tid << 2);
    float4 eA = *(const float4*)(Et);
    float4 eB = *(const float4*)(Et + 1024);
    accA.x += eA.x; accA.y += eA.y; accA.z += eA.z; accA.w += eA.w;
    accB.x += eB.x; accB.y += eB.y; accB.z += eB.z; accB.w += eB.w;
    *(float4*)&gsh[tid << 2]          = accA;
    *(float4*)&gsh[1024 + (tid << 2)] = accB;
    __syncthreads();
    // pointwise: units u0=tid, u1=tid+256
    float gi0 = gsh[tid],       gf0 = gsh[512+tid],
          gg0 = gsh[1024+tid],  go0 = gsh[1536+tid];
    float gi1 = gsh[tid+256],   gf1 = gsh[768+tid],
          gg1 = gsh[1280+tid],  go1 = gsh[1792+tid];
    c0 = sigm(gf0) * c0 + sigm(gi0) * tanh_(gg0);
    c1 = sigm(gf1) * c1 + sigm(gi1) * tanh_(gg1);
    float h0 = sigm(go0) * tanh_(c0);
    float h1 = sigm(go1) * tanh_(c1);
    hsh[tid] = h0; hsh[tid + 256] = h1;
    float* eo = enc_out + ((size_t)b * S + t) * H;
    eo[tid] = h0; eo[tid + 256] = h1;
    __syncthreads();
  }
  c_buf[(size_t)b * H + tid]       = c0;
  c_buf[(size_t)b * H + 256 + tid] = c1;
}

// -------- per-batch decoder: grid=32 blocks, no grid sync --------
__global__ __launch_bounds__(256) void decoder_kernel(
    const float* __restrict__ WT,     // dec WhhT [512][2048]
    const float* __restrict__ D,      // [b][t][c] (enc_out@dWih^T + dbias)
    const float* __restrict__ dbias,  // [2048]
    const float* __restrict__ W2T,    // [512][512]
    const float* __restrict__ Pt,     // [b][h][s]
    const float* __restrict__ vvec,   // [512]
    const float* __restrict__ enc_out,// [b][t][h]
    const float* __restrict__ c_buf,  // [b][h]
    float* __restrict__ out)          // [b][t][s]
{
  __shared__ float hsh[H];
  __shared__ float gsh[G4];
  __shared__ float dpsh[H];
  __shared__ float vsh[H];
  __shared__ float scsh[2][S];
  __shared__ float wm[2]; __shared__ int wi[2]; __shared__ float wsum[2];
  const int tid = threadIdx.x, b = blockIdx.x;
  // init: h = enc_out[b][S-1], c from c_buf, v cached
  hsh[tid]       = enc_out[((size_t)b * S + (S-1)) * H + tid];
  hsh[tid + 256] = enc_out[((size_t)b * S + (S-1)) * H + 256 + tid];
  vsh[tid] = vvec[tid]; vsh[tid + 256] = vvec[tid + 256];
  float c0 = c_buf[(size_t)b * H + tid];
  float c1 = c_buf[(size_t)b * H + 256 + tid];
  int top = 0;
  __syncthreads();
  for (int t = 0; t < S; ++t){
    // ---- gates ----
    float4 accA, accB;
    gates_gemv(WT, hsh, tid, accA, accB);
    const float* xs = (t == 0) ? (dbias + (tid << 2))
                               : (D + ((size_t)b * S + top) * G4 + (tid << 2));
    float4 xA = *(const float4*)(xs);
    float4 xB = *(const float4*)(xs + 1024);
    accA.x += xA.x; accA.y += xA.y; accA.z += xA.z; accA.w += xA.w;
    accB.x += xB.x; accB.y += xB.y; accB.z += xB.z; accB.w += xB.w;
    *(float4*)&gsh[tid << 2]          = accA;
    *(float4*)&gsh[1024 + (tid << 2)] = accB;
    __syncthreads();
    // ---- pointwise ----
    float gi0 = gsh[tid],       gf0 = gsh[512+tid],
          gg0 = gsh[1024+tid],  go0 = gsh[1536+tid];
    float gi1 = gsh[tid+256],   gf1 = gsh[768+tid],
          gg1 = gsh[1280+tid],  go1 = gsh[1792+tid];
    c0 = sigm(gf0) * c0 + sigm(gi0) * tanh_(gg0);
    c1 = sigm(gf1) * c1 + sigm(gi1) * tanh_(gg1);
    hsh[tid]       = sigm(go0) * tanh_(c0);
    hsh[tid + 256] = sigm(go1) * tanh_(c1);
    __syncthreads();
    // ---- dp = h @ W2^T : thread computes rows 2*tid, 2*tid+1 ----
    float d0 = 0.f, d1 = 0.f;
    #pragma unroll 2
    for (int k = 0; k < H; k += 4){
      float4 hv = *(const float4*)&hsh[k];
      const float* w = W2T + (size_t)k * H + (tid << 1);
      float2 w0 = *(const float2*)(w);
      float2 w1 = *(const float2*)(w + H);
      float2 w2 = *(const float2*)(w + 2*H);
      float2 w3 = *(const float2*)(w + 3*H);
      d0 = fmaf(w0.x, hv.x, d0); d1 = fmaf(w0.y, hv.x, d1);
      d0 = fmaf(w1.x, hv.y, d0); d1 = fmaf(w1.y, hv.y, d1);
      d0 = fmaf(w2.x, hv.z, d0); d1 = fmaf(w2.y, hv.z, d1);
      d0 = fmaf(w3.x, hv.w, d0); d1 = fmaf(w3.y, hv.w, d1);
    }
    *(float2*)&dpsh[tid << 1] = make_float2(d0, d1);
    __syncthreads();
    // ---- attention scores: thread (s = tid&127, half = tid>>7) ----
    {
      int s = tid & 127, half = tid >> 7;
      const float* Pp = Pt + ((size_t)b * H + half * 256) * S + s;
      const float* dq = dpsh + half * 256;
      const float* vq = vsh + half * 256;
      float cs = 0.f;
      #pragma unroll 4
      for (int hh = 0; hh < 256; ++hh){
        float x = Pp[(size_t)hh * S] + dq[hh];
        cs = fmaf(vq[hh], tanh_(x), cs);
      }
      scsh[half][s] = cs;
    }
    __syncthreads();
    // ---- argmax + log-softmax over 128 scores (threads 0..127, 2 waves) ----
    float sc = 0.f;
    if (tid < 128){
      sc = scsh[0][tid] + scsh[1][tid];
      float mv = sc; int mi = tid;
      #pragma unroll
      for (int off = 32; off > 0; off >>= 1){
        float ov = __shfl_xor(mv, off, 64);
        int   oi = __shfl_xor(mi, off, 64);
        if (ov > mv || (ov == mv && oi < mi)){ mv = ov; mi = oi; }
      }
      if ((tid & 63) == 0){ wm[tid >> 6] = mv; wi[tid >> 6] = mi; }
    }
    __syncthreads();
    float m; int am;
    {
      float m0 = wm[0], m1 = wm[1];
      if (m1 > m0 || (m1 == m0 && wi[1] < wi[0])){ m = m1; am = wi[1]; }
      else { m = m0; am = wi[0]; }
    }
    if (tid < 128){
      float se = __expf(sc - m);
      float ss = se;
      #pragma unroll
      for (int off = 32; off > 0; off >>= 1) ss += __shfl_xor(ss, off, 64);
      if ((tid & 63) == 0) wsum[tid >> 6] = ss;
    }
    __syncthreads();
    float lse = __logf(wsum[0] + wsum[1]);
    if (tid < 128) out[((size_t)b * S + t) * S + tid] = sc - m - lse;
    top = am;
    __syncthreads();
  }
}

extern "C" void kernel_launch(void* const* d_in, const int* in_sizes, int n_in,
                              void* d_out, int out_size, void* d_ws, size_t ws_size,
                              hipStream_t stream) {
  const float* inputs  = (const float*)d_in[0];
  const float* Wp      = (const float*)d_in[1];
  const float* bp      = (const float*)d_in[2];
  const float* eWih    = (const float*)d_in[3];
  const float* eWhh    = (const float*)d_in[4];
  const float* ebih    = (const float*)d_in[5];
  const float* ebhh    = (const float*)d_in[6];
  const float* dWih    = (const float*)d_in[7];
  const float* dWhh    = (const float*)d_in[8];
  const float* dbih    = (const float*)d_in[9];
  const float* dbhh    = (const float*)d_in[10];
  const float* W1      = (const float*)d_in[11];
  const float* W2      = (const float*)d_in[12];
  const float* v       = (const float*)d_in[13];
  float* out = (float*)d_out;

  float* ws = (float*)d_ws;
  float* E       = ws + OFF_E;    // also D after encoder
  float* enc_out = ws + OFF_EO;
  float* Pt      = ws + OFF_PT;
  float* WET     = ws + OFF_WET;
  float* WDT     = ws + OFF_WDT;
  float* W2T     = ws + OFF_W2T;
  float* c_buf   = ws + OFF_CB;
  float* M1      = ws + OFF_M1;
  float* bias_e  = ws + OFF_BE;
  float* dbias   = ws + OFF_DB;

  prep_misc<<<G4 / 256, 256, 0, stream>>>(eWih, Wp, bp, ebih, ebhh, dbih, dbhh,
                                          M1, bias_e, dbias);
  efill<<<(int)(SZ_E / 256), 256, 0, stream>>>(inputs, M1, bias_e, E);

  { dim3 g(H/32, G4/32); transpose_k<<<g, 256, 0, stream>>>(eWhh, WET, G4, H); }
  { dim3 g(H/32, G4/32); transpose_k<<<g, 256, 0, stream>>>(dWhh, WDT, G4, H); }
  { dim3 g(H/32, H/32);  transpose_k<<<g, 256, 0, stream>>>(W2,   W2T, H,  H); }

  encoder_kernel<<<32, 256, 0, stream>>>(WET, E, enc_out, c_buf);

  // D = enc_out @ dWih^T + dbias  (reuses E's buffer; encoder is done with E)
  float* D = E;
  { dim3 grid(G4 / 64, (B * S) / 64);
    gemm_nt<0><<<grid, 256, 0, stream>>>(enc_out, dWih, dbias, D, B * S, G4, H); }
  { dim3 grid(H / 64, (B * S) / 64);
    gemm_nt<1><<<grid, 256, 0, stream>>>(enc_out, W1, nullptr, Pt, B * S, H, H); }

  decoder_kernel<<<32, 256, 0, stream>>>(WDT, D, dbias, W2T, Pt, v,
                                         enc_out, c_buf, out);
  (void)in_sizes; (void)n_in; (void)out_size; (void)ws_size;
}